// Round 8
// baseline (559.291 us; speedup 1.0000x reference)
//
#include <hip/hip_runtime.h>
#include <hip/hip_bf16.h>

typedef unsigned short ushort_t;

#define B_ 64
#define S_ 512
#define E_ 256
#define H_ 128
#define M_ (B_ * S_)   // 32768 rows
#define CAP_ 128       // max neighbor slots (nnz ~ Binom(512,0.05): mean 25.6, max ~55)

// Y (GEMM out / aggf in): CHUNKED [b][chunk=col/16][512][16]
// h (aggf out / GEMM in): row-major [row][128]

// ---------------------------------------------------------------------------
// K1: neighbor lists from binary adj (float4 reads) + invdeg = 1/(nnz+1)
// ---------------------------------------------------------------------------
__global__ void k_adjidx(const float* __restrict__ adj,
                         ushort_t* __restrict__ idxl,
                         int* __restrict__ nnz,
                         float* __restrict__ invdeg) {
    int row  = blockIdx.x * 4 + (threadIdx.x >> 6);
    int lane = threadIdx.x & 63;
    const float4* arow = (const float4*)(adj + (size_t)row * S_);
    ushort_t* dst = idxl + (size_t)row * CAP_;
    int total = 0;
    #pragma unroll
    for (int c = 0; c < 2; ++c) {
        float4 v = arow[c * 64 + lane];
        float f[4] = {v.x, v.y, v.z, v.w};
        #pragma unroll
        for (int j = 0; j < 4; ++j) {
            unsigned long long m = __ballot(f[j] != 0.0f);
            if (f[j] != 0.0f) {
                int pos = total + __popcll(m & ((1ull << lane) - 1ull));
                if (pos < CAP_) dst[pos] = (ushort_t)(c * 256 + lane * 4 + j);
            }
            total += __popcll(m);
        }
    }
    if (lane == 0) {
        nnz[row] = total < CAP_ ? total : CAP_;
        invdeg[row] = 1.0f / (float)(total + 1);
    }
}

// ---------------------------------------------------------------------------
// K2: barrier-light GEMM  Y[row, colBase:+64] = X[row, :] @ W[cols, :]^T
// BM=128 (4 waves x 32 rows), BN=64. Internal loop over 128-k halves:
// W half-slab in LDS (2 barriers per half); X streamed through a per-wave
// private LDS slab (same-wave DS ordering -> no barriers in the k-loop).
// Output written CHUNKED-16.
// ---------------------------------------------------------------------------
template <int K, bool GATHER>
__global__ __launch_bounds__(256, 2) void k_gemm(const float* __restrict__ X,
                                                 const int* __restrict__ sent,
                                                 const float* __restrict__ emb,
                                                 const float* __restrict__ W,
                                                 float* __restrict__ out) {
    __shared__ float Ws[128 * 68];     // [k][64 cols + pad] 34816 B
    __shared__ float Xs[4][16 * 36];   // per-wave [k16][32 rows + pad] 9216 B
    int tid  = threadIdx.x;
    int wave = tid >> 6, lane = tid & 63;
    int rb      = blockIdx.x >> 1;
    int colBase = (blockIdx.x & 1) * 64;
    int rowBase = rb * 128 + wave * 32;

    int cc = lane & 15, rr = lane >> 4;    // micro-tile: 8 rows x 4 cols
    int kg = lane & 3,  rowi = lane >> 2;  // staging: rows (rowi, rowi+16), k-grp kg

    const float* xs0;
    const float* xs1;
    if (GATHER) {
        xs0 = emb + (size_t)sent[rowBase + rowi]      * K + kg * 4;
        xs1 = emb + (size_t)sent[rowBase + rowi + 16] * K + kg * 4;
    } else {
        xs0 = X + (size_t)(rowBase + rowi)      * K + kg * 4;
        xs1 = X + (size_t)(rowBase + rowi + 16) * K + kg * 4;
    }

    float acc[8][4] = {};
    float* xsw = Xs[wave];

    for (int kh = 0; kh < K; kh += 128) {
        if (kh) __syncthreads();           // all waves done reading prior Ws
        {   // W half-slab load (transpose to k-major)
            int j  = tid & 63;
            int kq = tid >> 6;
            const float* wp = W + (size_t)(colBase + j) * K + kh + kq * 32;
            #pragma unroll
            for (int i = 0; i < 8; ++i) {
                float4 v = *(const float4*)(wp + i * 4);
                int k = kq * 32 + i * 4;
                Ws[(k + 0) * 68 + j] = v.x; Ws[(k + 1) * 68 + j] = v.y;
                Ws[(k + 2) * 68 + j] = v.z; Ws[(k + 3) * 68 + j] = v.w;
            }
        }
        float4 f0 = *(const float4*)(xs0 + kh);
        float4 f1 = *(const float4*)(xs1 + kh);
        __syncthreads();                   // Ws ready

        #pragma unroll 1
        for (int kk = 0; kk < 128; kk += 16) {
            xsw[(kg * 4 + 0) * 36 + rowi] = f0.x;
            xsw[(kg * 4 + 1) * 36 + rowi] = f0.y;
            xsw[(kg * 4 + 2) * 36 + rowi] = f0.z;
            xsw[(kg * 4 + 3) * 36 + rowi] = f0.w;
            xsw[(kg * 4 + 0) * 36 + rowi + 16] = f1.x;
            xsw[(kg * 4 + 1) * 36 + rowi + 16] = f1.y;
            xsw[(kg * 4 + 2) * 36 + rowi + 16] = f1.z;
            xsw[(kg * 4 + 3) * 36 + rowi + 16] = f1.w;
            if (kk + 16 < 128) {           // prefetch next chunk
                f0 = *(const float4*)(xs0 + kh + kk + 16);
                f1 = *(const float4*)(xs1 + kh + kk + 16);
            }
            #pragma unroll
            for (int k = 0; k < 16; ++k) {
                float4 a0 = *(const float4*)&xsw[k * 36 + rr * 8];
                float4 a1 = *(const float4*)&xsw[k * 36 + rr * 8 + 4];
                float4 wv = *(const float4*)&Ws[(kk + k) * 68 + cc * 4];
                float xv[8] = {a0.x, a0.y, a0.z, a0.w, a1.x, a1.y, a1.z, a1.w};
                #pragma unroll
                for (int i = 0; i < 8; ++i) {
                    acc[i][0] += xv[i] * wv.x;
                    acc[i][1] += xv[i] * wv.y;
                    acc[i][2] += xv[i] * wv.z;
                    acc[i][3] += xv[i] * wv.w;
                }
            }
        }
    }

    int col   = colBase + cc * 4;
    int chunk = col >> 4, jc = col & 15;
    #pragma unroll
    for (int i = 0; i < 8; ++i) {
        int row = rowBase + rr * 8 + i;
        int bb  = row >> 9, r = row & 511;
        float4 o = {acc[i][0], acc[i][1], acc[i][2], acc[i][3]};
        *(float4*)(out + (((size_t)bb * 8 + chunk) * 512 + r) * 16 + jc) = o;
    }
}

// ---------------------------------------------------------------------------
// K3: conflict-free LDS-slab aggregate. One block per (batch, 16-col chunk):
// slab s[512][17] (stride 17 = odd -> banks spread). A wave processes 4 rows
// (slots) x 16 cols: the gather row index is UNIFORM across a slot's 16
// lanes -> each gather is 16 consecutive dwords (<=2-way banks, free).
// Neighbor-index loads are slot-uniform (merged); pipelined one ahead.
//   h[row] = relu((Y[row] + sum_nbr Y[t] + 2b) * invdeg[row])
// POOL: block-max over 512 rows -> pooled[b][ch*16..+15].
// ---------------------------------------------------------------------------
template <bool POOL>
__global__ __launch_bounds__(256) void k_aggf(const float* __restrict__ Y,
                                              const ushort_t* __restrict__ idxl,
                                              const int* __restrict__ nnz,
                                              const float* __restrict__ invdeg,
                                              const float* __restrict__ bias,
                                              float* __restrict__ out) {
    __shared__ float s[512 * 17];          // 34816 B
    __shared__ float red[256];
    int blk  = blockIdx.x;
    int xcd  = blk & 7, slot7 = blk >> 3;  // XCD swizzle: batch pinned to XCD
    int b    = xcd + 8 * (slot7 >> 3);
    int ch   = slot7 & 7;
    int tid  = threadIdx.x;

    const float4* g4 = (const float4*)(Y + ((size_t)b * 8 + ch) * 512 * 16);
    #pragma unroll
    for (int i = 0; i < 8; ++i) {
        int idx = tid + i * 256;
        int r = idx >> 2, c4 = idx & 3;
        *(float4*)&s[r * 17 + c4 * 4] = g4[idx];
    }
    __syncthreads();

    int wave = tid >> 6, lane = tid & 63;
    int slot = lane >> 4, col = lane & 15;
    float b2 = 2.0f * bias[ch * 16 + col];
    float vmax = -1e30f;

    #pragma unroll 1
    for (int it = 0; it < 32; ++it) {
        int r   = wave * 128 + it * 4 + slot;
        int row = b * S_ + r;
        int n   = nnz[row];
        const ushort_t* il = idxl + (size_t)row * CAP_;
        float acc = s[r * 17 + col];
        int idx = (n > 0) ? il[0] : 0;
        for (int t = 0; t < n; ++t) {
            int nidx = (t + 1 < n) ? il[t + 1] : 0;   // prefetch next index
            acc += s[idx * 17 + col];
            idx = nidx;
        }
        float o = fmaxf((acc + b2) * invdeg[row], 0.0f);
        if (POOL) vmax = fmaxf(vmax, o);
        else      out[(size_t)row * H_ + ch * 16 + col] = o;
    }

    if (POOL) {
        red[tid] = vmax;
        __syncthreads();
        if (tid < 16) {
            float m = red[tid];
            #pragma unroll
            for (int g = 1; g < 16; ++g) m = fmaxf(m, red[g * 16 + tid]);
            out[(size_t)b * H_ + ch * 16 + tid] = m;
        }
    }
}

// ---------------------------------------------------------------------------
// K4: logits[b,c] = pooled[b,:] . Wp[c,:] + bp[c]   (pooled is [64][128])
// ---------------------------------------------------------------------------
__global__ void k_final(const float* __restrict__ pooled,
                        const float* __restrict__ Wp,
                        const float* __restrict__ bp,
                        float* __restrict__ out) {
    int b = blockIdx.x, j = threadIdx.x;  // 128 threads
    float m = pooled[(size_t)b * H_ + j];
    float t0 = m * Wp[j];
    float t1 = m * Wp[H_ + j];
    #pragma unroll
    for (int off = 32; off > 0; off >>= 1) {
        t0 += __shfl_down(t0, off);
        t1 += __shfl_down(t1, off);
    }
    __shared__ float red[2][2];
    int wave = j >> 6, lane = j & 63;
    if (lane == 0) { red[0][wave] = t0; red[1][wave] = t1; }
    __syncthreads();
    if (j == 0) out[b * 2 + 0] = red[0][0] + red[0][1] + bp[0];
    if (j == 1) out[b * 2 + 1] = red[1][0] + red[1][1] + bp[1];
}

// ---------------------------------------------------------------------------
extern "C" void kernel_launch(void* const* d_in, const int* in_sizes, int n_in,
                              void* d_out, int out_size, void* d_ws, size_t ws_size,
                              hipStream_t stream) {
    const int*   sent = (const int*)d_in[0];
    const float* adj  = (const float*)d_in[1];
    const float* emb  = (const float*)d_in[2];
    const float* W1   = (const float*)d_in[3];
    const float* b1   = (const float*)d_in[4];
    const float* W2   = (const float*)d_in[5];
    const float* b2   = (const float*)d_in[6];
    const float* W3   = (const float*)d_in[7];
    const float* b3   = (const float*)d_in[8];
    const float* Wp   = (const float*)d_in[9];
    const float* bp   = (const float*)d_in[10];
    float* out = (float*)d_out;

    char* ws = (char*)d_ws;
    float*    Ybuf   = (float*)ws;                              // 16 MiB, chunked
    float*    h1     = (float*)(ws + ((size_t)16 << 20));       // 16 MiB
    float*    h2     = (float*)(ws + ((size_t)32 << 20));       // 16 MiB
    char*     base   = ws + ((size_t)48 << 20);
    float*    invdeg = (float*)base;                            // M f32
    int*      nnz    = (int*)(base + (size_t)M_ * 4);
    ushort_t* idxl   = (ushort_t*)(base + (size_t)M_ * 8);      // M*CAP u16 = 8 MiB
    float*    pooled = (float*)(base + (size_t)M_ * 8 + (size_t)M_ * CAP_ * 2);  // 64*128 f32

    k_adjidx<<<M_ / 4, 256, 0, stream>>>(adj, idxl, nnz, invdeg);

    // layer 1 (K=256, fused embedding gather, internal split-K)
    k_gemm<E_, true ><<<512, 256, 0, stream>>>(nullptr, sent, emb, W1, Ybuf);
    k_aggf<false><<<512, 256, 0, stream>>>(Ybuf, idxl, nnz, invdeg, b1, h1);

    // layer 2
    k_gemm<H_, false><<<512, 256, 0, stream>>>(h1, nullptr, nullptr, W2, Ybuf);
    k_aggf<false><<<512, 256, 0, stream>>>(Ybuf, idxl, nnz, invdeg, b2, h2);

    // layer 3 (+fused max-pool)
    k_gemm<H_, false><<<512, 256, 0, stream>>>(h2, nullptr, nullptr, W3, Ybuf);
    k_aggf<true ><<<512, 256, 0, stream>>>(Ybuf, idxl, nnz, invdeg, b3, pooled);

    k_final<<<B_, H_, 0, stream>>>(pooled, Wp, bp, out);
}

// Round 9
// 296.002 us; speedup vs baseline: 1.8895x; 1.8895x over previous
//
#include <hip/hip_runtime.h>
#include <hip/hip_bf16.h>

typedef unsigned short ushort_t;

#define B_ 64
#define S_ 512
#define E_ 256
#define H_ 128
#define M_ (B_ * S_)   // 32768 rows
#define CAP_ 128       // max neighbor slots (nnz ~ Binom(512,0.05): mean 25.6, max ~55)

// Y (GEMM out / aggf in): row-major [row][128]
// h (aggf out / GEMM in): row-major [row][128]

// ---------------------------------------------------------------------------
// K1: neighbor lists from binary adj (float4 reads) + invdeg = 1/(nnz+1)
// ---------------------------------------------------------------------------
__global__ void k_adjidx(const float* __restrict__ adj,
                         ushort_t* __restrict__ idxl,
                         int* __restrict__ nnz,
                         float* __restrict__ invdeg) {
    int row  = blockIdx.x * 4 + (threadIdx.x >> 6);
    int lane = threadIdx.x & 63;
    const float4* arow = (const float4*)(adj + (size_t)row * S_);
    ushort_t* dst = idxl + (size_t)row * CAP_;
    int total = 0;
    #pragma unroll
    for (int c = 0; c < 2; ++c) {
        float4 v = arow[c * 64 + lane];
        float f[4] = {v.x, v.y, v.z, v.w};
        #pragma unroll
        for (int j = 0; j < 4; ++j) {
            unsigned long long m = __ballot(f[j] != 0.0f);
            if (f[j] != 0.0f) {
                int pos = total + __popcll(m & ((1ull << lane) - 1ull));
                if (pos < CAP_) dst[pos] = (ushort_t)(c * 256 + lane * 4 + j);
            }
            total += __popcll(m);
        }
    }
    if (lane == 0) {
        nnz[row] = total < CAP_ ? total : CAP_;
        invdeg[row] = 1.0f / (float)(total + 1);
    }
}

// ---------------------------------------------------------------------------
// K2: barrier-light GEMM  Y[row, colBase:+64] = X[row, :] @ W[cols, :]^T
// (measured ~12-15us/dispatch in round 8). BM=128 (4 waves x 32 rows), BN=64.
// Internal loop over 128-k halves: W half-slab in LDS (2 barriers per half);
// X streamed through a per-wave private LDS slab (same-wave DS ordering ->
// no barriers inside the k-loop). Output row-major.
// ---------------------------------------------------------------------------
template <int K, bool GATHER>
__global__ __launch_bounds__(256, 2) void k_gemm(const float* __restrict__ X,
                                                 const int* __restrict__ sent,
                                                 const float* __restrict__ emb,
                                                 const float* __restrict__ W,
                                                 float* __restrict__ out) {
    __shared__ float Ws[128 * 68];     // [k][64 cols + pad] 34816 B
    __shared__ float Xs[4][16 * 36];   // per-wave [k16][32 rows + pad] 9216 B
    int tid  = threadIdx.x;
    int wave = tid >> 6, lane = tid & 63;
    int rb      = blockIdx.x >> 1;
    int colBase = (blockIdx.x & 1) * 64;
    int rowBase = rb * 128 + wave * 32;

    int cc = lane & 15, rr = lane >> 4;    // micro-tile: 8 rows x 4 cols
    int kg = lane & 3,  rowi = lane >> 2;  // staging: rows (rowi, rowi+16), k-grp kg

    const float* xs0;
    const float* xs1;
    if (GATHER) {
        xs0 = emb + (size_t)sent[rowBase + rowi]      * K + kg * 4;
        xs1 = emb + (size_t)sent[rowBase + rowi + 16] * K + kg * 4;
    } else {
        xs0 = X + (size_t)(rowBase + rowi)      * K + kg * 4;
        xs1 = X + (size_t)(rowBase + rowi + 16) * K + kg * 4;
    }

    float acc[8][4] = {};
    float* xsw = Xs[wave];

    for (int kh = 0; kh < K; kh += 128) {
        if (kh) __syncthreads();           // all waves done reading prior Ws
        {   // W half-slab load (transpose to k-major)
            int j  = tid & 63;
            int kq = tid >> 6;
            const float* wp = W + (size_t)(colBase + j) * K + kh + kq * 32;
            #pragma unroll
            for (int i = 0; i < 8; ++i) {
                float4 v = *(const float4*)(wp + i * 4);
                int k = kq * 32 + i * 4;
                Ws[(k + 0) * 68 + j] = v.x; Ws[(k + 1) * 68 + j] = v.y;
                Ws[(k + 2) * 68 + j] = v.z; Ws[(k + 3) * 68 + j] = v.w;
            }
        }
        float4 f0 = *(const float4*)(xs0 + kh);
        float4 f1 = *(const float4*)(xs1 + kh);
        __syncthreads();                   // Ws ready

        #pragma unroll 1
        for (int kk = 0; kk < 128; kk += 16) {
            xsw[(kg * 4 + 0) * 36 + rowi] = f0.x;
            xsw[(kg * 4 + 1) * 36 + rowi] = f0.y;
            xsw[(kg * 4 + 2) * 36 + rowi] = f0.z;
            xsw[(kg * 4 + 3) * 36 + rowi] = f0.w;
            xsw[(kg * 4 + 0) * 36 + rowi + 16] = f1.x;
            xsw[(kg * 4 + 1) * 36 + rowi + 16] = f1.y;
            xsw[(kg * 4 + 2) * 36 + rowi + 16] = f1.z;
            xsw[(kg * 4 + 3) * 36 + rowi + 16] = f1.w;
            if (kk + 16 < 128) {           // prefetch next chunk
                f0 = *(const float4*)(xs0 + kh + kk + 16);
                f1 = *(const float4*)(xs1 + kh + kk + 16);
            }
            #pragma unroll
            for (int k = 0; k < 16; ++k) {
                float4 a0 = *(const float4*)&xsw[k * 36 + rr * 8];
                float4 a1 = *(const float4*)&xsw[k * 36 + rr * 8 + 4];
                float4 wv = *(const float4*)&Ws[(kk + k) * 68 + cc * 4];
                float xv[8] = {a0.x, a0.y, a0.z, a0.w, a1.x, a1.y, a1.z, a1.w};
                #pragma unroll
                for (int i = 0; i < 8; ++i) {
                    acc[i][0] += xv[i] * wv.x;
                    acc[i][1] += xv[i] * wv.y;
                    acc[i][2] += xv[i] * wv.z;
                    acc[i][3] += xv[i] * wv.w;
                }
            }
        }
    }

    #pragma unroll
    for (int i = 0; i < 8; ++i) {
        int row = rowBase + rr * 8 + i;
        float4 o = {acc[i][0], acc[i][1], acc[i][2], acc[i][3]};
        *(float4*)(out + (size_t)row * H_ + colBase + cc * 4) = o;
    }
}

// ---------------------------------------------------------------------------
// K3: global-gather aggregate (round-2 design, measured ~15-20us):
//   h[row] = relu( (Y[row] + sum_{t in nbr(row)} Y[b,t] + 2b) * invdeg[row] )
// 256 threads = 8 rows x 32 float4-lanes; XCD-swizzled so each batch's 256KB
// Y slab stays in one XCD's L2; gathers are float4, 4-way unrolled.
// POOL: block-max over its 8 rows -> pp partial [b*64+g][128].
// ---------------------------------------------------------------------------
template <bool POOL>
__global__ __launch_bounds__(256) void k_aggf(const float* __restrict__ Y,
                                              const ushort_t* __restrict__ idxl,
                                              const int* __restrict__ nnz,
                                              const float* __restrict__ invdeg,
                                              const float* __restrict__ bias,
                                              float* __restrict__ out) {
    int x    = blockIdx.x;            // 0..4095
    int xcd  = x & 7;
    int slot = x >> 3;                // 0..511
    int b    = xcd + 8 * (slot >> 6); // fixed xcd per batch
    int g    = slot & 63;
    int r    = threadIdx.x >> 5;      // 0..7
    int row  = b * S_ + g * 8 + r;
    int c    = threadIdx.x & 31;

    const float4* Y4 = (const float4*)Y;
    int n = nnz[row];
    const ushort_t* il = idxl + (size_t)row * CAP_;
    float4 acc = Y4[(size_t)row * 32 + c];
    float4 acc2 = {0.f, 0.f, 0.f, 0.f};
    size_t base = (size_t)b * S_ * 32;

    int i = 0;
    for (; i + 4 <= n; i += 4) {
        int t0 = il[i], t1 = il[i + 1], t2 = il[i + 2], t3 = il[i + 3];
        float4 v0 = Y4[base + (size_t)t0 * 32 + c];
        float4 v1 = Y4[base + (size_t)t1 * 32 + c];
        float4 v2 = Y4[base + (size_t)t2 * 32 + c];
        float4 v3 = Y4[base + (size_t)t3 * 32 + c];
        acc.x += v0.x + v1.x; acc.y += v0.y + v1.y;
        acc.z += v0.z + v1.z; acc.w += v0.w + v1.w;
        acc2.x += v2.x + v3.x; acc2.y += v2.y + v3.y;
        acc2.z += v2.z + v3.z; acc2.w += v2.w + v3.w;
    }
    for (; i < n; ++i) {
        int t = il[i];
        float4 v = Y4[base + (size_t)t * 32 + c];
        acc.x += v.x; acc.y += v.y; acc.z += v.z; acc.w += v.w;
    }
    acc.x += acc2.x; acc.y += acc2.y; acc.z += acc2.z; acc.w += acc2.w;

    float inv = invdeg[row];
    float4 bv = ((const float4*)bias)[c];
    float4 o;
    o.x = fmaxf((acc.x + 2.0f * bv.x) * inv, 0.0f);
    o.y = fmaxf((acc.y + 2.0f * bv.y) * inv, 0.0f);
    o.z = fmaxf((acc.z + 2.0f * bv.z) * inv, 0.0f);
    o.w = fmaxf((acc.w + 2.0f * bv.w) * inv, 0.0f);

    if (!POOL) {
        ((float4*)out)[(size_t)row * 32 + c] = o;
    } else {
        __shared__ float4 sm[8][33];
        sm[r][c] = o;
        __syncthreads();
        if (r == 0) {
            float4 m = sm[0][c];
            #pragma unroll
            for (int q = 1; q < 8; ++q) {
                float4 v = sm[q][c];
                m.x = fmaxf(m.x, v.x); m.y = fmaxf(m.y, v.y);
                m.z = fmaxf(m.z, v.z); m.w = fmaxf(m.w, v.w);
            }
            ((float4*)out)[((size_t)b * 64 + g) * 32 + c] = m;   // pp partial
        }
    }
}

// ---------------------------------------------------------------------------
// K4: finish pool (64 partials) + logits[b,c] = pooled . Wp[c,:] + bp[c]
// ---------------------------------------------------------------------------
__global__ void k_final(const float* __restrict__ pp,
                        const float* __restrict__ Wp,
                        const float* __restrict__ bp,
                        float* __restrict__ out) {
    int b = blockIdx.x, j = threadIdx.x;  // 128 threads
    const float* p = pp + (size_t)b * 64 * H_ + j;
    float m = -1e30f;
    #pragma unroll 8
    for (int i = 0; i < 64; ++i) m = fmaxf(m, p[(size_t)i * H_]);
    float t0 = m * Wp[j];
    float t1 = m * Wp[H_ + j];
    #pragma unroll
    for (int off = 32; off > 0; off >>= 1) {
        t0 += __shfl_down(t0, off);
        t1 += __shfl_down(t1, off);
    }
    __shared__ float red[2][2];
    int wave = j >> 6, lane = j & 63;
    if (lane == 0) { red[0][wave] = t0; red[1][wave] = t1; }
    __syncthreads();
    if (j == 0) out[b * 2 + 0] = red[0][0] + red[0][1] + bp[0];
    if (j == 1) out[b * 2 + 1] = red[1][0] + red[1][1] + bp[1];
}

// ---------------------------------------------------------------------------
extern "C" void kernel_launch(void* const* d_in, const int* in_sizes, int n_in,
                              void* d_out, int out_size, void* d_ws, size_t ws_size,
                              hipStream_t stream) {
    const int*   sent = (const int*)d_in[0];
    const float* adj  = (const float*)d_in[1];
    const float* emb  = (const float*)d_in[2];
    const float* W1   = (const float*)d_in[3];
    const float* b1   = (const float*)d_in[4];
    const float* W2   = (const float*)d_in[5];
    const float* b2   = (const float*)d_in[6];
    const float* W3   = (const float*)d_in[7];
    const float* b3   = (const float*)d_in[8];
    const float* Wp   = (const float*)d_in[9];
    const float* bp   = (const float*)d_in[10];
    float* out = (float*)d_out;

    char* ws = (char*)d_ws;
    float*    Ybuf   = (float*)ws;                              // 16 MiB
    float*    h1     = (float*)(ws + ((size_t)16 << 20));       // 16 MiB
    float*    h2     = (float*)(ws + ((size_t)32 << 20));       // 16 MiB
    char*     base   = ws + ((size_t)48 << 20);
    float*    invdeg = (float*)base;                            // M f32
    int*      nnz    = (int*)(base + (size_t)M_ * 4);
    ushort_t* idxl   = (ushort_t*)(base + (size_t)M_ * 8);      // M*CAP u16 = 8 MiB
    float*    pp     = (float*)(base + (size_t)M_ * 8 + (size_t)M_ * CAP_ * 2);  // 64*64*128 f32

    k_adjidx<<<M_ / 4, 256, 0, stream>>>(adj, idxl, nnz, invdeg);

    // layer 1 (K=256, fused embedding gather, internal split-K)
    k_gemm<E_, true ><<<512, 256, 0, stream>>>(nullptr, sent, emb, W1, Ybuf);
    k_aggf<false><<<M_ / 8, 256, 0, stream>>>(Ybuf, idxl, nnz, invdeg, b1, h1);

    // layer 2
    k_gemm<H_, false><<<512, 256, 0, stream>>>(h1, nullptr, nullptr, W2, Ybuf);
    k_aggf<false><<<M_ / 8, 256, 0, stream>>>(Ybuf, idxl, nnz, invdeg, b2, h2);

    // layer 3 (+fused max-pool partials)
    k_gemm<H_, false><<<512, 256, 0, stream>>>(h2, nullptr, nullptr, W3, Ybuf);
    k_aggf<true ><<<M_ / 8, 256, 0, stream>>>(Ybuf, idxl, nnz, invdeg, b3, pp);

    k_final<<<B_, H_, 0, stream>>>(pp, Wp, bp, out);
}